// Round 20
// baseline (42.698 us; speedup 1.0000x reference)
//
#include <hip/hip_runtime.h>

#define LEN_EPISODE 2048
#define TW 6.283185307179586
#define HH 0.16

// R19 (resubmit; prior round died on infra): checkpoint two-phase replaces
// redundant integration.
// Phase 1: wave 0 ALONE integrates all 128 RK4(h=0.16) iters (no emit, no
// co-resident contention -- waves 1-7 parked at barrier issue nothing),
// storing (U,V) at each of 8 chunk starts into LDS (4KB).
// Phase 2: wave w loads checkpoint w, rotor re-derived from f64 libm (done in
// setup = free during phase-1 idle), emits its 16-iter window (15 Hermite +
// endpoint, LDS-transposed coalesced flush -- all validated R16-R18).
// Wall = 128*p_solo + 16*e + barrier; dur directly measures p_solo.

#define STEPH() do {                                                        \
    const float f1 = Atil * rcf;                                            \
    const float f2 = __builtin_fmaf(nA2s, rsf, A2c * rcf);                  \
    const float f3 = __builtin_fmaf(nA3s, rsf, A3c * rcf);                  \
    rcn = __builtin_fmaf(nsdf, rsf, rcf * cdf);                             \
    rsn = __builtin_fmaf(sdf, rcf, rsf * cdf);                              \
    const float f4 = Atil * rcn;                                            \
    const float s1 = __builtin_amdgcn_sinf(U);                              \
    const float U2 = __builtin_fmaf(c13, V, U);                             \
    const float s2 = __builtin_amdgcn_sinf(U2);                             \
    const float k1w = __builtin_fmaf(nw2t, s1, __builtin_fmaf(ngam, V, f1)); \
    const float V2 = __builtin_fmaf(c13, k1w, V);                           \
    const float k2w = __builtin_fmaf(nw2t, s2, __builtin_fmaf(ngam, V2, f2)); \
    const float U3 = __builtin_fmaf(hh, V2, __builtin_fmaf(nc13, V, U));    \
    const float V3 = __builtin_fmaf(hh, k2w, __builtin_fmaf(nc13, k1w, V)); \
    const float s3 = __builtin_amdgcn_sinf(U3);                             \
    const float k3w = __builtin_fmaf(nw2t, s3, __builtin_fmaf(ngam, V3, f3)); \
    const float U4 = __builtin_fmaf(hh, (V - V2) + V3, U);                  \
    const float V4 = __builtin_fmaf(hh, (k1w - k2w) + k3w, V);              \
    const float s4 = __builtin_amdgcn_sinf(U4);                             \
    const float k4w = __builtin_fmaf(nw2t, s4, __builtin_fmaf(ngam, V4, f4)); \
    Un = __builtin_fmaf(h8, __builtin_fmaf(3.0f, V2 + V3, V) + V4, U);      \
    Vn = __builtin_fmaf(h8, __builtin_fmaf(3.0f, k2w + k3w, k1w) + k4w, V); \
} while (0)

// Cubic Hermite basis (compile-time doubles), radians+h folded in.
#define B00(t) ((1.0-(t))*(1.0-(t))*(1.0+2.0*(t)))
#define B10(t) ((t)*(1.0-(t))*(1.0-(t)))
#define B01(t) ((t)*(t)*(3.0-2.0*(t)))
#define B11(t) ((t)*(t)*((t)-1.0))
#define HERMT(t)                                                              \
    __builtin_fmaf((float)(TW * B00(t)), U,                                   \
    __builtin_fmaf((float)(TW * B10(t) * HH), V,                              \
    __builtin_fmaf((float)(TW * B01(t)), Un, (float)(TW * B11(t) * HH) * Vn)))

#define EMIT15(dst) do {                                                      \
    (dst)[0]  = HERMT( 1.0/16.0); (dst)[1]  = HERMT( 2.0/16.0);               \
    (dst)[2]  = HERMT( 3.0/16.0); (dst)[3]  = HERMT( 4.0/16.0);               \
    (dst)[4]  = HERMT( 5.0/16.0); (dst)[5]  = HERMT( 6.0/16.0);               \
    (dst)[6]  = HERMT( 7.0/16.0); (dst)[7]  = HERMT( 8.0/16.0);               \
    (dst)[8]  = HERMT( 9.0/16.0); (dst)[9]  = HERMT(10.0/16.0);               \
    (dst)[10] = HERMT(11.0/16.0); (dst)[11] = HERMT(12.0/16.0);               \
    (dst)[12] = HERMT(13.0/16.0); (dst)[13] = HERMT(14.0/16.0);               \
    (dst)[14] = HERMT(15.0/16.0);                                             \
} while (0)

#define COMMIT() do { U = Un; V = Vn; rcf = rcn; rsf = rsn; } while (0)

__global__ __launch_bounds__(512) void pend_kernel(
    const float* __restrict__ init,    // (B, 2)
    const float* __restrict__ params,  // (B, 4)
    float* __restrict__ out,           // (B, LEN_EPISODE)
    int B)
{
    __shared__ float lds[8 * 16 * 65]; // per-wave [16 samples][65] staging
    __shared__ float ckU[8][64];       // checkpoint theta (rev) at chunk start
    __shared__ float ckV[8][64];       // checkpoint w (rev/s)

    const int tid  = threadIdx.x;
    const int lane = tid & 63;
    const int wv   = tid >> 6;          // wave 0..7 = chunk 0..7
    const int b = blockIdx.x * 64 + lane;   // grid exactly covers B=16384

    const float2 ic = *reinterpret_cast<const float2*>(init + 2 * b);
    const float4 p  = *reinterpret_cast<const float4*>(params + 4 * b);
    const float omega = p.x, gamma = p.y, A = p.z, phi = p.w;

    const float twopi  = 6.283185307179586f;
    const float inv2pi = 0.15915494309189535f;

    float U = ic.x * inv2pi;            // theta in revolutions
    float V = ic.y * inv2pi;            // w in rev/s

    const float hh   = 0.16f;           // big step h = 16*dt
    const float c13  = (float)(0.16 / 3.0);
    const float nc13 = -c13;
    const float h8   = 0.02f;           // h/8
    const float ngam = -gamma;
    const float nw2t = -(omega * omega) * inv2pi;
    const float Atil = A * omega * omega * inv2pi;

    // ---- rotor constants (f64 libm once; loop is pure f32) ----
    const double c_d = 6.283185307179586476925287 * (double)phi;  // 2*pi*phi
    const float cdf  = (float)::cos(c_d * 0.16);
    const float sdf  = (float)::sin(c_d * 0.16);
    const float nsdf = -sdf;
    const float A2c  = Atil * (float)::cos(c_d * (0.16 / 3.0));
    const float nA2s = -Atil * (float)::sin(c_d * (0.16 / 3.0));
    const float A3c  = Atil * (float)::cos(c_d * (0.32 / 3.0));
    const float nA3s = -Atil * (float)::sin(c_d * (0.32 / 3.0));
    // this wave's phase-2 rotor start at t = kbeg*h (free: during phase-1 idle)
    const int kbeg = wv << 4;
    const double t0 = 0.16 * (double)kbeg;
    const float rc0 = (float)::cos(c_d * t0);
    const float rs0 = (float)::sin(c_d * t0);

    float rcf = 1.0f, rsf = 0.0f;       // f32 rotor: cos/sin(c*t), t=0
    float Un, Vn, rcn, rsn;

    // ---- phase 1: wave 0 solo-integrates 128 iters, checkpoints every 16 ----
    if (wv == 0) {
        for (int c = 0; c < 8; ++c) {
            ckU[c][lane] = U;
            ckV[c][lane] = V;
#pragma unroll 4
            for (int j = 0; j < 16; ++j) { STEPH(); COMMIT(); }
        }
    }
    __syncthreads();

    // ---- phase 2: every wave emits its 16-iter window from its checkpoint ----
    U = ckU[wv][lane];
    V = ckV[wv][lane];
    rcf = rc0; rsf = rs0;

    // Flush mapping: 16 cols/iter; 4 lanes cover one row's 16 floats (64B).
    const int r16 = lane >> 2;
    const int q2  = lane & 3;
    float* __restrict__ outblk = out + (size_t)(blockIdx.x * 64) * LEN_EPISODE;
    float* __restrict__ ldsw = lds + wv * (16 * 65);

    float va[16];

    for (int k = kbeg; k < kbeg + 16; ++k) {
        va[0] = (k == 0) ? ic.x : twopi * U;   // previous endpoint
        STEPH(); EMIT15(va + 1); COMMIT();

#pragma unroll
        for (int j = 0; j < 16; ++j)
            ldsw[j * 65 + lane] = va[j];

        const int colb = k << 4;
#pragma unroll
        for (int rb = 0; rb < 4; ++rb) {
            const int row = (rb << 4) + r16;
            float4 v;
            v.x = ldsw[(4 * q2 + 0) * 65 + row];
            v.y = ldsw[(4 * q2 + 1) * 65 + row];
            v.z = ldsw[(4 * q2 + 2) * 65 + row];
            v.w = ldsw[(4 * q2 + 3) * 65 + row];
            *reinterpret_cast<float4*>(outblk + (size_t)row * LEN_EPISODE + colb + 4 * q2) = v;
        }
    }
    // final endpoint (output index 2048) intentionally discarded
}

extern "C" void kernel_launch(void* const* d_in, const int* in_sizes, int n_in,
                              void* d_out, int out_size, void* d_ws, size_t ws_size,
                              hipStream_t stream) {
    const float* init   = (const float*)d_in[0];
    const float* params = (const float*)d_in[1];
    float* out = (float*)d_out;
    const int B = in_sizes[0] / 2;  // 16384

    const int block = 512;              // 8 waves: checkpoint two-phase
    const int grid  = B / 64;           // exact cover, no tail
    pend_kernel<<<grid, block, 0, stream>>>(init, params, out, B);
}

// Round 21
// 32.175 us; speedup vs baseline: 1.3271x; 1.3271x over previous
//
#include <hip/hip_runtime.h>

#define LEN_EPISODE 2048
#define TW 6.283185307179586
#define HH 0.16

// R21: producer/consumer wave specialization.
// Diagnosis from R20's regression: R18's wall = partial overlap of two ~21us
// terms -- the 128-step serial chain (~165ns/step) and the 134MB output-write
// stream (~21us at HBM write ceiling). Emit iters stall the emitting wave's
// own chain. Fix: wave 0 = pure producer (STEPH only; publishes (U,V) per
// step to a 64-deep LDS ring; no global stores on its chain). Waves
// 1-3,5-7 = 6 emitters on SIMDs 1-3 (producer owns SIMD 0; wave 4 exits):
// emitter e handles steps k == e (mod 6): spin on LDS counter, read ring,
// 15 Hermite + endpoint, transpose-stage, coalesced flush (R16-validated
// pattern). Emitter capacity ~6x producer rate -> writes spread uniformly;
// chain runs unstalled. Math bit-identical to R18 => absmax must be 0.875.

#define STEPH() do {                                                        \
    const float f1 = Atil * rcf;                                            \
    const float f2 = __builtin_fmaf(nA2s, rsf, A2c * rcf);                  \
    const float f3 = __builtin_fmaf(nA3s, rsf, A3c * rcf);                  \
    rcn = __builtin_fmaf(nsdf, rsf, rcf * cdf);                             \
    rsn = __builtin_fmaf(sdf, rcf, rsf * cdf);                              \
    const float f4 = Atil * rcn;                                            \
    const float s1 = __builtin_amdgcn_sinf(U);                              \
    const float U2 = __builtin_fmaf(c13, V, U);                             \
    const float s2 = __builtin_amdgcn_sinf(U2);                             \
    const float k1w = __builtin_fmaf(nw2t, s1, __builtin_fmaf(ngam, V, f1)); \
    const float V2 = __builtin_fmaf(c13, k1w, V);                           \
    const float k2w = __builtin_fmaf(nw2t, s2, __builtin_fmaf(ngam, V2, f2)); \
    const float U3 = __builtin_fmaf(hh, V2, __builtin_fmaf(nc13, V, U));    \
    const float V3 = __builtin_fmaf(hh, k2w, __builtin_fmaf(nc13, k1w, V)); \
    const float s3 = __builtin_amdgcn_sinf(U3);                             \
    const float k3w = __builtin_fmaf(nw2t, s3, __builtin_fmaf(ngam, V3, f3)); \
    const float U4 = __builtin_fmaf(hh, (V - V2) + V3, U);                  \
    const float V4 = __builtin_fmaf(hh, (k1w - k2w) + k3w, V);              \
    const float s4 = __builtin_amdgcn_sinf(U4);                             \
    const float k4w = __builtin_fmaf(nw2t, s4, __builtin_fmaf(ngam, V4, f4)); \
    Un = __builtin_fmaf(h8, __builtin_fmaf(3.0f, V2 + V3, V) + V4, U);      \
    Vn = __builtin_fmaf(h8, __builtin_fmaf(3.0f, k2w + k3w, k1w) + k4w, V); \
} while (0)

// Cubic Hermite basis (compile-time doubles), radians+h folded in.
#define B00(t) ((1.0-(t))*(1.0-(t))*(1.0+2.0*(t)))
#define B10(t) ((t)*(1.0-(t))*(1.0-(t)))
#define B01(t) ((t)*(t)*(3.0-2.0*(t)))
#define B11(t) ((t)*(t)*((t)-1.0))
#define HERMT(t)                                                              \
    __builtin_fmaf((float)(TW * B00(t)), U,                                   \
    __builtin_fmaf((float)(TW * B10(t) * HH), V,                              \
    __builtin_fmaf((float)(TW * B01(t)), Un, (float)(TW * B11(t) * HH) * Vn)))

#define EMIT15(dst) do {                                                      \
    (dst)[0]  = HERMT( 1.0/16.0); (dst)[1]  = HERMT( 2.0/16.0);               \
    (dst)[2]  = HERMT( 3.0/16.0); (dst)[3]  = HERMT( 4.0/16.0);               \
    (dst)[4]  = HERMT( 5.0/16.0); (dst)[5]  = HERMT( 6.0/16.0);               \
    (dst)[6]  = HERMT( 7.0/16.0); (dst)[7]  = HERMT( 8.0/16.0);               \
    (dst)[8]  = HERMT( 9.0/16.0); (dst)[9]  = HERMT(10.0/16.0);               \
    (dst)[10] = HERMT(11.0/16.0); (dst)[11] = HERMT(12.0/16.0);               \
    (dst)[12] = HERMT(13.0/16.0); (dst)[13] = HERMT(14.0/16.0);               \
    (dst)[14] = HERMT(15.0/16.0);                                             \
} while (0)

#define COMMIT() do { U = Un; V = Vn; rcf = rcn; rsf = rsn; } while (0)

__global__ __launch_bounds__(512) void pend_kernel(
    const float* __restrict__ init,    // (B, 2)
    const float* __restrict__ params,  // (B, 4)
    float* __restrict__ out,           // (B, LEN_EPISODE)
    int B)
{
    __shared__ float2 ring[64][64];    // [slot = k&63][lane] = (U,V) at t_k
    __shared__ float  stag[6][16 * 65];// per-emitter transpose staging
    __shared__ int    cnt;             // number of published slots

    const int tid  = threadIdx.x;
    const int lane = tid & 63;
    const int wv   = tid >> 6;          // 0 = producer; 1-3,5-7 = emitters
    const int b = blockIdx.x * 64 + lane;

    const float twopi  = 6.283185307179586f;
    const float inv2pi = 0.15915494309189535f;

    const float2 ic = *reinterpret_cast<const float2*>(init + 2 * b);

    if (tid == 0) cnt = 0;
    __syncthreads();                    // cnt initialized before anyone spins

    if (wv == 0) {
        // ---------------- producer: pure integration ----------------
        const float4 p  = *reinterpret_cast<const float4*>(params + 4 * b);
        const float omega = p.x, gamma = p.y, A = p.z, phi = p.w;

        float U = ic.x * inv2pi;
        float V = ic.y * inv2pi;

        const float hh   = 0.16f;
        const float c13  = (float)(0.16 / 3.0);
        const float nc13 = -c13;
        const float h8   = 0.02f;
        const float ngam = -gamma;
        const float nw2t = -(omega * omega) * inv2pi;
        const float Atil = A * omega * omega * inv2pi;

        const double c_d = 6.283185307179586476925287 * (double)phi;
        const float cdf  = (float)::cos(c_d * 0.16);
        const float sdf  = (float)::sin(c_d * 0.16);
        const float nsdf = -sdf;
        const float A2c  = Atil * (float)::cos(c_d * (0.16 / 3.0));
        const float nA2s = -Atil * (float)::sin(c_d * (0.16 / 3.0));
        const float A3c  = Atil * (float)::cos(c_d * (0.32 / 3.0));
        const float nA3s = -Atil * (float)::sin(c_d * (0.32 / 3.0));

        float rcf = 1.0f, rsf = 0.0f;
        float Un, Vn, rcn, rsn;

        for (int k = 0; k < 128; ++k) {
            ring[k & 63][lane] = make_float2(U, V);
            __threadfence_block();                      // drain slot writes
            if (lane == 0)
                __hip_atomic_store(&cnt, k + 1, __ATOMIC_RELEASE,
                                   __HIP_MEMORY_SCOPE_WORKGROUP);
            STEPH(); COMMIT();
        }
        ring[128 & 63][lane] = make_float2(U, V);       // final endpoint state
        __threadfence_block();
        if (lane == 0)
            __hip_atomic_store(&cnt, 129, __ATOMIC_RELEASE,
                               __HIP_MEMORY_SCOPE_WORKGROUP);
    } else if (wv != 4) {
        // ---------------- emitters: Hermite + transposed flush ----------------
        const int eid = (wv < 4) ? (wv - 1) : (wv - 2);   // 0..5
        float* __restrict__ stg = &stag[eid][0];
        const int r16 = lane >> 2;          // row within 16-row group
        const int q2  = lane & 3;           // 16B column chunk
        float* __restrict__ outblk = out + (size_t)(blockIdx.x * 64) * LEN_EPISODE;

        float va[16];

        for (int k = eid; k < 128; k += 6) {
            // wait until slots k and k+1 are published
            while (__hip_atomic_load(&cnt, __ATOMIC_ACQUIRE,
                                     __HIP_MEMORY_SCOPE_WORKGROUP) < k + 2) {
                __builtin_amdgcn_s_sleep(1);
            }
            const float2 s0 = ring[k & 63][lane];
            const float2 s1 = ring[(k + 1) & 63][lane];
            const float U = s0.x, V = s0.y, Un = s1.x, Vn = s1.y;

            va[0] = (k == 0) ? ic.x : twopi * U;    // previous endpoint
            EMIT15(va + 1);

#pragma unroll
            for (int j = 0; j < 16; ++j)
                stg[j * 65 + lane] = va[j];

            const int colb = k << 4;
#pragma unroll
            for (int rb = 0; rb < 4; ++rb) {
                const int row = (rb << 4) + r16;
                float4 v;
                v.x = stg[(4 * q2 + 0) * 65 + row];
                v.y = stg[(4 * q2 + 1) * 65 + row];
                v.z = stg[(4 * q2 + 2) * 65 + row];
                v.w = stg[(4 * q2 + 3) * 65 + row];
                *reinterpret_cast<float4*>(outblk + (size_t)row * LEN_EPISODE + colb + 4 * q2) = v;
            }
        }
    }
    // wave 4 (shares SIMD 0 with producer): exits after the barrier
    // final endpoint (output index 2048) intentionally discarded
}

extern "C" void kernel_launch(void* const* d_in, const int* in_sizes, int n_in,
                              void* d_out, int out_size, void* d_ws, size_t ws_size,
                              hipStream_t stream) {
    const float* init   = (const float*)d_in[0];
    const float* params = (const float*)d_in[1];
    float* out = (float*)d_out;
    const int B = in_sizes[0] / 2;  // 16384

    const int block = 512;              // wave 0 producer, 6 emitter waves
    const int grid  = B / 64;           // 256 blocks, exact cover
    pend_kernel<<<grid, block, 0, stream>>>(init, params, out, B);
}